// Round 2
// baseline (5716.175 us; speedup 1.0000x reference)
//
#include <hip/hip_runtime.h>

typedef float floatx4 __attribute__((ext_vector_type(4)));

#define MDIM 4096
#define HDIM 4096
#define IDIM 14336
#define FP8MAX 448.0f

// ---------------------------------------------------------------------------
// LDS tile: 128 rows x 128 fp8 cols, row stride 128B, 16B-chunk XOR swizzle
// (chunk c stored at c ^ (row & 7)) -> ds_read_b64 fragments conflict-free.
// ---------------------------------------------------------------------------
__device__ __forceinline__ long ld_frag(const unsigned char* lds, int row, int k8) {
  const int c = k8 >> 1;
  const int off = (row << 7) + ((c ^ (row & 7)) << 4) + ((k8 & 1) << 3);
  return *(const long*)(lds + off);
}

__device__ __forceinline__ void stage_tile(const unsigned char* __restrict__ gp,
                                           unsigned char* lds, int tid, int stride) {
#pragma unroll
  for (int p = 0; p < 4; ++p) {
    const int idx = (p << 8) + tid;
    const int r = idx >> 3, c = idx & 7;
    const uint4 v = *(const uint4*)(gp + (size_t)r * stride + (c << 4));
    *(uint4*)(lds + (r << 7) + ((c ^ (r & 7)) << 4)) = v;
  }
}

// ---------------------------------------------------------------------------
// Weight-dtype detection. fp8-e4m3 values are exact in bf16/fp32 with known
// zero low bits: fp32-of-e4m3 -> low 20 bits zero; bf16-of-e4m3 -> low 4 bits
// of each halfword zero; raw fp8 bytes -> neither (P(pass) ~ 0).
// flag: 2 = fp32, 1 = bf16, 0 = raw fp8 bytes.
// ---------------------------------------------------------------------------
__global__ void detect_dtype(const unsigned int* __restrict__ w, int* __restrict__ flag) {
  if (threadIdx.x == 0 && blockIdx.x == 0) {
    bool f32 = true, b16 = true;
    for (int i = 0; i < 64; ++i) {
      const unsigned int v = w[i];
      if (v & 0xFFFFFu) f32 = false;
      if ((v & 0xFu) || ((v >> 16) & 0xFu)) b16 = false;
    }
    *flag = f32 ? 2 : (b16 ? 1 : 0);
  }
}

__device__ __forceinline__ float bfu(unsigned int bits16) {
  union { unsigned int u; float f; } c;
  c.u = bits16 << 16;
  return c.f;
}

__device__ __forceinline__ unsigned int pack2(unsigned int lo, unsigned int hi) {
  // lo, hi each hold two bf16 (elements 0,1 and 2,3)
  int pk = __builtin_amdgcn_cvt_pk_fp8_f32(bfu(lo & 0xFFFFu), bfu(lo >> 16), 0, false);
  pk = __builtin_amdgcn_cvt_pk_fp8_f32(bfu(hi & 0xFFFFu), bfu(hi >> 16), pk, true);
  return (unsigned int)pk;
}

// Convert one weight matrix (n elements, n % 4096 == 0) to fp8 bytes in dst.
__global__ __launch_bounds__(256) void conv_w(const void* __restrict__ src,
                                              unsigned char* __restrict__ dst,
                                              const int* __restrict__ flag_p) {
  const int flag = *flag_p;
  const long t = (long)blockIdx.x * 256 + threadIdx.x;  // 16 elements per thread
  uint4 out;
  if (flag == 2) {
    const float4* s = (const float4*)src;
    unsigned int o[4];
#pragma unroll
    for (int p = 0; p < 4; ++p) {
      const float4 v = s[t * 4 + p];
      int pk = __builtin_amdgcn_cvt_pk_fp8_f32(v.x, v.y, 0, false);
      pk = __builtin_amdgcn_cvt_pk_fp8_f32(v.z, v.w, pk, true);
      o[p] = (unsigned int)pk;
    }
    out = make_uint4(o[0], o[1], o[2], o[3]);
  } else if (flag == 1) {
    const uint4* s = (const uint4*)src;
    const uint4 a = s[t * 2], b = s[t * 2 + 1];
    out = make_uint4(pack2(a.x, a.y), pack2(a.z, a.w),
                     pack2(b.x, b.y), pack2(b.z, b.w));
  } else {
    out = ((const uint4*)src)[t];
  }
  ((uint4*)dst)[t] = out;
}

// ---------------------------------------------------------------------------
// Kernel 1: fake-quant activations. One wave per (row, 128-col group).
// ---------------------------------------------------------------------------
__global__ __launch_bounds__(256) void fq_act(const float* __restrict__ x,
                                              unsigned char* __restrict__ xq,
                                              float* __restrict__ xsT) {
  const int tid = threadIdx.x;
  const int lane = tid & 63, w = tid >> 6;
  const int g = blockIdx.x * 4 + w;  // M * H/128 = 131072 groups
  const int row = g >> 5, kb = g & 31;

  const float2 v = ((const float2*)(x + (size_t)row * HDIM + kb * 128))[lane];
  float amax = fmaxf(fabsf(v.x), fabsf(v.y));
#pragma unroll
  for (int off = 1; off < 64; off <<= 1)
    amax = fmaxf(amax, __shfl_xor(amax, off, 64));

  const float scale = fmaxf(amax / FP8MAX, 1e-12f);
  const float q0 = fminf(fmaxf(v.x / scale, -FP8MAX), FP8MAX);
  const float q1 = fminf(fmaxf(v.y / scale, -FP8MAX), FP8MAX);
  const int pk = __builtin_amdgcn_cvt_pk_fp8_f32(q0, q1, 0, false);
  ((unsigned short*)(xq + (size_t)row * HDIM + kb * 128))[lane] = (unsigned short)(pk & 0xFFFF);
  if (lane == 0) xsT[(size_t)kb * MDIM + row] = scale;
}

// ---------------------------------------------------------------------------
// Kernel 2: fused gate/up blockwise-fp8 GEMM + silu*u + per-row-128 fake quant.
// ---------------------------------------------------------------------------
__global__ __launch_bounds__(256, 2)
void dual_gemm_silu_fq(const unsigned char* __restrict__ xq, const float* __restrict__ xsT,
                       const unsigned char* __restrict__ gw, const float* __restrict__ gs,
                       const unsigned char* __restrict__ uw, const float* __restrict__ us,
                       unsigned char* __restrict__ hq, float* __restrict__ hsT) {
  __shared__ __align__(16) unsigned char lA[16384];
  __shared__ __align__(16) unsigned char lG[16384];
  __shared__ __align__(16) unsigned char lU[16384];
  __shared__ float lxs[128];

  const int tid = threadIdx.x;
  const int lane = tid & 63, wid = tid >> 6;
  const int quad = lane >> 4, l16 = lane & 15;
  const int bid = blockIdx.x;
  const int mi = bid & 31;   // M/128 inner -> weight-strip L2 reuse
  const int ni = bid >> 5;   // I/128 = 112
  const size_t m0 = (size_t)mi << 7, n0 = (size_t)ni << 7;

  floatx4 accG[2][8], accU[2][8];
#pragma unroll
  for (int mt = 0; mt < 2; ++mt)
#pragma unroll
    for (int nt = 0; nt < 8; ++nt) {
      accG[mt][nt] = {0.f, 0.f, 0.f, 0.f};
      accU[mt][nt] = {0.f, 0.f, 0.f, 0.f};
    }

  for (int kb = 0; kb < 32; ++kb) {
    stage_tile(xq + m0 * HDIM + kb * 128, lA, tid, HDIM);
    stage_tile(gw + n0 * HDIM + kb * 128, lG, tid, HDIM);
    stage_tile(uw + n0 * HDIM + kb * 128, lU, tid, HDIM);
    if (tid < 128) lxs[tid] = xsT[(size_t)kb * MDIM + m0 + tid];
    __syncthreads();

    const float sg = gs[ni * 32 + kb];
    const float su = us[ni * 32 + kb];
    float xsv[2][4];
#pragma unroll
    for (int mt = 0; mt < 2; ++mt)
#pragma unroll
      for (int r = 0; r < 4; ++r)
        xsv[mt][r] = lxs[wid * 32 + mt * 16 + quad * 4 + r];

    floatx4 blk[2][8];

    // ---- gate pass ----
#pragma unroll
    for (int mt = 0; mt < 2; ++mt)
#pragma unroll
      for (int nt = 0; nt < 8; ++nt) blk[mt][nt] = {0.f, 0.f, 0.f, 0.f};
#pragma unroll
    for (int ks = 0; ks < 4; ++ks) {
      const int k8 = ks * 4 + quad;
      const long aF0 = ld_frag(lA, wid * 32 + l16, k8);
      const long aF1 = ld_frag(lA, wid * 32 + 16 + l16, k8);
#pragma unroll
      for (int nt = 0; nt < 8; ++nt) {
        const long bF = ld_frag(lG, nt * 16 + l16, k8);
        blk[0][nt] = __builtin_amdgcn_mfma_f32_16x16x32_fp8_fp8(aF0, bF, blk[0][nt], 0, 0, 0);
        blk[1][nt] = __builtin_amdgcn_mfma_f32_16x16x32_fp8_fp8(aF1, bF, blk[1][nt], 0, 0, 0);
      }
    }
#pragma unroll
    for (int mt = 0; mt < 2; ++mt) {
      float pr[4];
#pragma unroll
      for (int r = 0; r < 4; ++r) pr[r] = xsv[mt][r] * sg;
#pragma unroll
      for (int nt = 0; nt < 8; ++nt)
#pragma unroll
        for (int r = 0; r < 4; ++r) accG[mt][nt][r] += blk[mt][nt][r] * pr[r];
    }

    // ---- up pass ----
#pragma unroll
    for (int mt = 0; mt < 2; ++mt)
#pragma unroll
      for (int nt = 0; nt < 8; ++nt) blk[mt][nt] = {0.f, 0.f, 0.f, 0.f};
#pragma unroll
    for (int ks = 0; ks < 4; ++ks) {
      const int k8 = ks * 4 + quad;
      const long aF0 = ld_frag(lA, wid * 32 + l16, k8);
      const long aF1 = ld_frag(lA, wid * 32 + 16 + l16, k8);
#pragma unroll
      for (int nt = 0; nt < 8; ++nt) {
        const long bF = ld_frag(lU, nt * 16 + l16, k8);
        blk[0][nt] = __builtin_amdgcn_mfma_f32_16x16x32_fp8_fp8(aF0, bF, blk[0][nt], 0, 0, 0);
        blk[1][nt] = __builtin_amdgcn_mfma_f32_16x16x32_fp8_fp8(aF1, bF, blk[1][nt], 0, 0, 0);
      }
    }
#pragma unroll
    for (int mt = 0; mt < 2; ++mt) {
      float pr[4];
#pragma unroll
      for (int r = 0; r < 4; ++r) pr[r] = xsv[mt][r] * su;
#pragma unroll
      for (int nt = 0; nt < 8; ++nt)
#pragma unroll
        for (int r = 0; r < 4; ++r) accU[mt][nt][r] += blk[mt][nt][r] * pr[r];
    }
    __syncthreads();
  }

  // ---- epilogue: h = silu(g)*u, per-row fake quant over this 128-col group --
#pragma unroll
  for (int mt = 0; mt < 2; ++mt) {
    float h[8][4];
    float amax[4] = {0.f, 0.f, 0.f, 0.f};
#pragma unroll
    for (int nt = 0; nt < 8; ++nt)
#pragma unroll
      for (int r = 0; r < 4; ++r) {
        const float g = accG[mt][nt][r];
        const float u = accU[mt][nt][r];
        const float hv = (g / (1.f + __expf(-g))) * u;
        h[nt][r] = hv;
        amax[r] = fmaxf(amax[r], fabsf(hv));
      }
#pragma unroll
    for (int off = 1; off < 16; off <<= 1)
#pragma unroll
      for (int r = 0; r < 4; ++r)
        amax[r] = fmaxf(amax[r], __shfl_xor(amax[r], off, 64));

    float scale[4];
#pragma unroll
    for (int r = 0; r < 4; ++r) scale[r] = fmaxf(amax[r] / FP8MAX, 1e-12f);

    const int rowl = wid * 32 + mt * 16 + quad * 4;
    if (l16 == 0) {
#pragma unroll
      for (int r = 0; r < 4; ++r)
        hsT[(size_t)ni * MDIM + m0 + rowl + r] = scale[r];
    }
#pragma unroll
    for (int nt = 0; nt < 8; ++nt)
#pragma unroll
      for (int r = 0; r < 4; ++r) {
        const float q = fminf(fmaxf(h[nt][r] / scale[r], -FP8MAX), FP8MAX);
        const int pk = __builtin_amdgcn_cvt_pk_fp8_f32(q, 0.f, 0, false);
        hq[(m0 + rowl + r) * (size_t)IDIM + n0 + nt * 16 + l16] = (unsigned char)(pk & 0xFF);
      }
  }
}

// ---------------------------------------------------------------------------
// Kernel 3: down projection, blockwise-fp8 GEMM, fp32 output.
// ---------------------------------------------------------------------------
__global__ __launch_bounds__(256, 2)
void gemm_down(const unsigned char* __restrict__ hq, const float* __restrict__ hsT,
               const unsigned char* __restrict__ dw, const float* __restrict__ dsc,
               float* __restrict__ out) {
  __shared__ __align__(16) unsigned char lA[16384];
  __shared__ __align__(16) unsigned char lB[16384];
  __shared__ float lhs[128];

  const int tid = threadIdx.x;
  const int lane = tid & 63, wid = tid >> 6;
  const int quad = lane >> 4, l16 = lane & 15;
  const int bid = blockIdx.x;
  const int mi = bid & 31;   // M/128
  const int ni = bid >> 5;   // H/128 = 32
  const size_t m0 = (size_t)mi << 7, n0 = (size_t)ni << 7;

  floatx4 acc[2][8];
#pragma unroll
  for (int mt = 0; mt < 2; ++mt)
#pragma unroll
    for (int nt = 0; nt < 8; ++nt) acc[mt][nt] = {0.f, 0.f, 0.f, 0.f};

  for (int kb = 0; kb < 112; ++kb) {
    stage_tile(hq + m0 * IDIM + kb * 128, lA, tid, IDIM);
    stage_tile(dw + n0 * IDIM + kb * 128, lB, tid, IDIM);
    if (tid < 128) lhs[tid] = hsT[(size_t)kb * MDIM + m0 + tid];
    __syncthreads();

    const float sd = dsc[ni * 112 + kb];
    float hv[2][4];
#pragma unroll
    for (int mt = 0; mt < 2; ++mt)
#pragma unroll
      for (int r = 0; r < 4; ++r)
        hv[mt][r] = lhs[wid * 32 + mt * 16 + quad * 4 + r] * sd;

    floatx4 blk[2][8];
#pragma unroll
    for (int mt = 0; mt < 2; ++mt)
#pragma unroll
      for (int nt = 0; nt < 8; ++nt) blk[mt][nt] = {0.f, 0.f, 0.f, 0.f};
#pragma unroll
    for (int ks = 0; ks < 4; ++ks) {
      const int k8 = ks * 4 + quad;
      const long aF0 = ld_frag(lA, wid * 32 + l16, k8);
      const long aF1 = ld_frag(lA, wid * 32 + 16 + l16, k8);
#pragma unroll
      for (int nt = 0; nt < 8; ++nt) {
        const long bF = ld_frag(lB, nt * 16 + l16, k8);
        blk[0][nt] = __builtin_amdgcn_mfma_f32_16x16x32_fp8_fp8(aF0, bF, blk[0][nt], 0, 0, 0);
        blk[1][nt] = __builtin_amdgcn_mfma_f32_16x16x32_fp8_fp8(aF1, bF, blk[1][nt], 0, 0, 0);
      }
    }
#pragma unroll
    for (int mt = 0; mt < 2; ++mt)
#pragma unroll
      for (int nt = 0; nt < 8; ++nt)
#pragma unroll
        for (int r = 0; r < 4; ++r) acc[mt][nt][r] += blk[mt][nt][r] * hv[mt][r];
    __syncthreads();
  }

#pragma unroll
  for (int mt = 0; mt < 2; ++mt) {
    const int rowl = wid * 32 + mt * 16 + quad * 4;
#pragma unroll
    for (int nt = 0; nt < 8; ++nt)
#pragma unroll
      for (int r = 0; r < 4; ++r)
        out[(m0 + rowl + r) * (size_t)HDIM + n0 + nt * 16 + l16] = acc[mt][nt][r];
  }
}

// ---------------------------------------------------------------------------
extern "C" void kernel_launch(void* const* d_in, const int* in_sizes, int n_in,
                              void* d_out, int out_size, void* d_ws, size_t ws_size,
                              hipStream_t stream) {
  const float* x   = (const float*)d_in[0];
  const void* gw_s = d_in[1];
  const float* gs  = (const float*)d_in[2];
  const void* uw_s = d_in[3];
  const float* us  = (const float*)d_in[4];
  const void* dw_s = d_in[5];
  const float* dsc = (const float*)d_in[6];
  float* out       = (float*)d_out;

  const size_t NW = (size_t)IDIM * HDIM;  // 58,720,256 elements per weight

  unsigned char* ws = (unsigned char*)d_ws;
  unsigned char* xq = ws;                         // 16 MB
  float* xsT = (float*)(ws + 16777216);           // 512 KB
  unsigned char* hq  = ws + 17301504;             // 56 MB
  float* hsT = (float*)(ws + 76021760);           // 1.75 MB
  unsigned char* gwq = ws + 77856768;             // 56 MB
  unsigned char* uwq = ws + 136577024;            // 56 MB
  unsigned char* dwq = gwq;                       // reuse gate slot after dual_gemm
  int* flag = (int*)(ws + 195297280);

  const bool fits = ws_size >= (size_t)195297284;
  const unsigned char* gwp = fits ? gwq : (const unsigned char*)gw_s;
  const unsigned char* uwp = fits ? uwq : (const unsigned char*)uw_s;
  const unsigned char* dwp = fits ? dwq : (const unsigned char*)dw_s;

  const int convBlocks = (int)(NW / (16 * 256));  // 14336, exact

  if (fits) {
    detect_dtype<<<1, 64, 0, stream>>>((const unsigned int*)gw_s, flag);
    conv_w<<<convBlocks, 256, 0, stream>>>(gw_s, gwq, flag);
    conv_w<<<convBlocks, 256, 0, stream>>>(uw_s, uwq, flag);
  }
  fq_act<<<(MDIM * (HDIM / 128)) / 4, 256, 0, stream>>>(x, xq, xsT);
  dual_gemm_silu_fq<<<(MDIM / 128) * (IDIM / 128), 256, 0, stream>>>(
      xq, xsT, gwp, gs, uwp, us, hq, hsT);
  if (fits) {
    conv_w<<<convBlocks, 256, 0, stream>>>(dw_s, dwq, flag);
  }
  gemm_down<<<(MDIM / 128) * (HDIM / 128), 256, 0, stream>>>(hq, hsT, dwp, dsc, out);
}